// Round 6
// baseline (966.981 us; speedup 1.0000x reference)
//
#include <hip/hip_runtime.h>
#include <math.h>

static constexpr int N_NODES = 100000;
static constexpr int N_EDGES = 1600000;
static constexpr int E_TOT   = N_NODES + N_EDGES;   // edges + self-loops
static constexpr int D   = 512;
static constexpr int FIN = 182;
static constexpr int K1P = 192;                     // FIN padded to mult of 64
static constexpr int M_PAD = 100096;                // 782 * 128
static constexpr float NEG_SLOPE = 0.2f;
static constexpr float LN_EPS = 1e-5f;

typedef __attribute__((ext_vector_type(8))) short short8;
typedef __attribute__((ext_vector_type(4))) float floatx4;
typedef __attribute__((ext_vector_type(2))) float floatx2;

// ---------------- bf16 helpers (storage type: unsigned short) ----------------
__device__ __forceinline__ unsigned short f2bf(float f) {
  unsigned int x = __builtin_bit_cast(unsigned int, f);
  x += 0x7fffu + ((x >> 16) & 1u);   // round-to-nearest-even
  return (unsigned short)(x >> 16);
}
__device__ __forceinline__ void unpack2(unsigned int w, float& lo, float& hi) {
  lo = __builtin_bit_cast(float, w << 16);
  hi = __builtin_bit_cast(float, w & 0xffff0000u);
}

// async global->LDS, 16B per lane; LDS dest = wave-uniform base + lane*16
typedef __attribute__((address_space(1))) const void gv_t;
typedef __attribute__((address_space(3))) void lv_t;
__device__ __forceinline__ void gll16(const void* g, void* l) {
  __builtin_amdgcn_global_load_lds((gv_t*)g, (lv_t*)l, 16, 0, 0);
}

// stage one BK=32 panel pair (A,B) into the given LDS buffers
__device__ __forceinline__ void stage4(const unsigned short* gA0, const unsigned short* gA1,
                                       const unsigned short* gB0, const unsigned short* gB1,
                                       unsigned short* As, unsigned short* Bs, int w, int k0) {
  gll16(gA0 + k0, As + (w * 2 + 0) * 512);
  gll16(gA1 + k0, As + (w * 2 + 1) * 512);
  gll16(gB0 + k0, Bs + (w * 2 + 0) * 512);
  gll16(gB1 + k0, Bs + (w * 2 + 1) * 512);
}

// ---------------------------------------------------------------------------
// init (deg zero + counter) with fused edge-index dtype probe (block 0)
// ---------------------------------------------------------------------------
__global__ __launch_bounds__(256) void k_init(const int* __restrict__ ei,
                                              int* __restrict__ deg,
                                              int* __restrict__ counter,
                                              int* __restrict__ flag) {
  int i = blockIdx.x * 256 + threadIdx.x;
  if (i < N_NODES) deg[i] = 0;
  if (blockIdx.x == 0) {
    bool nz = false;
#pragma unroll
    for (int rp = 0; rp < 8; ++rp) {
      int j = threadIdx.x + rp * 256;          // sample edges 0..2047
      nz |= (ei[2 * j + 1] != 0);
    }
    __shared__ int sh[4];
    int wv = threadIdx.x >> 6;
    if ((threadIdx.x & 63) == 0) sh[wv] = 0;
    __syncthreads();
    if (__any(nz) && (threadIdx.x & 63) == 0) sh[wv] = 1;
    __syncthreads();
    if (threadIdx.x == 0) {
      *flag = sh[0] | sh[1] | sh[2] | sh[3];
      *counter = 0;
    }
  }
}

__device__ __forceinline__ int edge_src(const int* ei, int f, int i) {
  return f ? ei[i] : ei[2 * i];
}
__device__ __forceinline__ int edge_dst(const int* ei, int f, int i) {
  return f ? ei[N_EDGES + i] : ei[2 * (N_EDGES + i)];
}

// ---------------------------------------------------------------------------
// CSR build grouped by dst (range order irrelevant -> atomic range alloc)
// ---------------------------------------------------------------------------
__global__ __launch_bounds__(256) void k_count(const int* __restrict__ ei,
                                               const int* __restrict__ flag,
                                               int* __restrict__ deg) {
  int i = blockIdx.x * 256 + threadIdx.x;
  if (i >= E_TOT) return;
  int f = *flag;
  int d = (i < N_EDGES) ? edge_dst(ei, f, i) : (i - N_EDGES);
  atomicAdd(deg + d, 1);
}

// also initializes out[n,0:2] = bc2 (atomic target for gemm_cls epilogue)
__global__ __launch_bounds__(256) void k_alloc(const int* __restrict__ deg,
                                               int* __restrict__ off,
                                               int* __restrict__ pos,
                                               int* __restrict__ counter,
                                               const float* __restrict__ bc2,
                                               float* __restrict__ out) {
  int i = blockIdx.x * 256 + threadIdx.x;
  if (i >= N_NODES) return;
  int r = atomicAdd(counter, deg[i]);
  off[i] = r;
  pos[i] = r;
  float2 v; v.x = bc2[0]; v.y = bc2[1];
  ((float2*)out)[i] = v;
}

__global__ __launch_bounds__(256) void k_fill(const int* __restrict__ ei,
                                              const int* __restrict__ flag,
                                              int* __restrict__ pos,
                                              int* __restrict__ csr_src) {
  int i = blockIdx.x * 256 + threadIdx.x;
  if (i >= E_TOT) return;
  int f = *flag;
  int s, d;
  if (i < N_EDGES) { s = edge_src(ei, f, i); d = edge_dst(ei, f, i); }
  else             { s = d = i - N_EDGES; }
  int slot = atomicAdd(pos + d, 1);
  csr_src[slot] = s;
}

// ---------------------------------------------------------------------------
// conversion kernels (one-shot, tiny)
// ---------------------------------------------------------------------------
__global__ __launch_bounds__(256) void k_cvt_x(const float* __restrict__ x,
                                               unsigned short* __restrict__ xb) {
  int i = blockIdx.x * 256 + threadIdx.x;
  if (i >= N_NODES * K1P) return;
  int row = i / K1P, col = i - row * K1P;
  float v = (col < FIN) ? x[(size_t)row * FIN + col] : 0.f;
  xb[i] = f2bf(v);
}

// all three weight transposes in one launch (blockIdx.y selects the weight)
__global__ __launch_bounds__(256) void k_cvt_w3(const float* __restrict__ W1,
                                                const float* __restrict__ W2,
                                                const float* __restrict__ Wc1,
                                                unsigned short* __restrict__ w1t,
                                                unsigned short* __restrict__ w2t,
                                                unsigned short* __restrict__ wc1t) {
  int i = blockIdx.x * 256 + threadIdx.x;
  int which = blockIdx.y;
  if (which == 0) {
    if (i >= 512 * K1P) return;
    int n = i / K1P, k = i - n * K1P;
    w1t[i] = f2bf(k < FIN ? W1[(size_t)k * 512 + n] : 0.f);
  } else if (which == 1) {
    if (i >= 512 * 512) return;
    int n = i >> 9, k = i & 511;
    w2t[i] = f2bf(W2[(size_t)k * 512 + n]);
  } else {
    if (i >= 512 * 512) return;
    int n = i >> 9, k = i & 511;
    wc1t[i] = f2bf(Wc1[(size_t)k * 512 + n]);
  }
}

// ---------------------------------------------------------------------------
// Fused GEMM + sdots: h = A @ Bt^T per-block as one full head (blockIdx.x ==
// head, 128 rows x 128 cols). Round-6 change: single-barrier 2-phase prefetch
// pipeline at BK=32 granularity -- the two 16 KB buffer sets ping-pong:
//   barrier -> issue STAGE(buf^1, k+32) -> compute(buf)
// so the barrier's vmcnt(0) waits on loads issued one full compute phase
// earlier (wait ~= latency - compute, not full latency). Same LDS (32 KB),
// same barrier count as round 5, numerics identical.
// Epilogue (proven round 1): in-block s_src/s_dst dots, per-(node,head)
// absmax, excess-128 int8 quantization.
// h8 row layout (permuted, per head block of 128 bytes): byte at local
// offset o encodes col (o&64) + 16*(o&3) + ((o>>2)&15).
// ---------------------------------------------------------------------------
__global__ __launch_bounds__(256)
void gemm_fused(const unsigned short* __restrict__ A,
                const unsigned short* __restrict__ Bt,
                const float* __restrict__ a_src,
                const float* __restrict__ a_dst,
                float2* __restrict__ ssc,
                float* __restrict__ s_dst,
                unsigned char* __restrict__ h8,
                int lda)
{
  __shared__ unsigned short As[2][128 * 32];   // ping-pong BK=32 buffers
  __shared__ unsigned short Bs[2][128 * 32];
  const int t    = threadIdx.x;
  const int w    = t >> 6;
  const int lane = t & 63;
  const int r    = lane & 15;
  const int q    = lane >> 4;
  const int bm   = blockIdx.y * 128;
  const int bn   = blockIdx.x * 128;        // bn/128 == head
  const int wm   = (w >> 1) * 64;
  const int wn   = (w & 1) * 64;

  const int ch0 = (w * 2 + 0) * 64 + lane;
  const int ch1 = (w * 2 + 1) * 64 + lane;
  const unsigned short* gA0 = A + (size_t)(bm + (ch0 >> 2)) * lda + (ch0 & 3) * 8;
  const unsigned short* gA1 = A + (size_t)(bm + (ch1 >> 2)) * lda + (ch1 & 3) * 8;
  const unsigned short* gB0 = Bt + (size_t)(bn + (ch0 >> 2)) * lda + (ch0 & 3) * 8;
  const unsigned short* gB1 = Bt + (size_t)(bn + (ch1 >> 2)) * lda + (ch1 & 3) * 8;

  floatx4 acc[4][4] = {};

  int cur = 0;
  stage4(gA0, gA1, gB0, gB1, &As[0][0], &Bs[0][0], w, 0);
  for (int k0 = 0; k0 < lda; k0 += 32) {
    __syncthreads();                       // stage(cur) landed; prev compute done
    if (k0 + 32 < lda)
      stage4(gA0, gA1, gB0, gB1, &As[cur ^ 1][0], &Bs[cur ^ 1][0], w, k0 + 32);
    short8 af[4], bfr[4];
#pragma unroll
    for (int im = 0; im < 4; ++im)
      af[im] = *(const short8*)(&As[cur][(wm + im * 16 + r) * 32 + q * 8]);
#pragma unroll
    for (int in = 0; in < 4; ++in)
      bfr[in] = *(const short8*)(&Bs[cur][(wn + in * 16 + r) * 32 + q * 8]);
#pragma unroll
    for (int im = 0; im < 4; ++im)
#pragma unroll
      for (int in = 0; in < 4; ++in)
        acc[im][in] = __builtin_amdgcn_mfma_f32_16x16x32_bf16(
            af[im], bfr[in], acc[im][in], 0, 0, 0);
    cur ^= 1;
  }
  __syncthreads();                         // all ds_reads done before LDS reuse

  // ---- fused sdots epilogue ----
  // C/D layout: local row lr = wm + im*16 + q*4 + rr, local col c = wn + in*16 + r
  float* sred = (float*)&As[0][0]; // [4 waves][64 rows][4: s_src, s_dst, absmax, pad]
  float* qscl = (float*)&Bs[0][0]; // [128 rows]

  float asv[4], adv[4];
#pragma unroll
  for (int in = 0; in < 4; ++in) {
    asv[in] = a_src[bn + wn + in * 16 + r];
    adv[in] = a_dst[bn + wn + in * 16 + r];
  }
#pragma unroll
  for (int im = 0; im < 4; ++im) {
    float ps_[4], pd_[4], pm_[4];
#pragma unroll
    for (int rr = 0; rr < 4; ++rr) {
      float s = 0.f, d = 0.f, m = 0.f;
#pragma unroll
      for (int in = 0; in < 4; ++in) {
        float v = acc[im][in][rr];
        s += v * asv[in];
        d += v * adv[in];
        m = fmaxf(m, fabsf(v));
      }
      ps_[rr] = s; pd_[rr] = d; pm_[rr] = m;
    }
#pragma unroll
    for (int o2 = 1; o2 < 16; o2 <<= 1) {
#pragma unroll
      for (int rr = 0; rr < 4; ++rr) {
        ps_[rr] += __shfl_xor(ps_[rr], o2);
        pd_[rr] += __shfl_xor(pd_[rr], o2);
        pm_[rr] = fmaxf(pm_[rr], __shfl_xor(pm_[rr], o2));
      }
    }
    if (r == 0) {
#pragma unroll
      for (int rr = 0; rr < 4; ++rr) {
        int r64 = im * 16 + q * 4 + rr;
        sred[(w * 64 + r64) * 4 + 0] = ps_[rr];
        sred[(w * 64 + r64) * 4 + 1] = pd_[rr];
        sred[(w * 64 + r64) * 4 + 2] = pm_[rr];
      }
    }
  }
  __syncthreads();

  if (t < 128) {
    int hf = t >> 6;                 // which wave pair (row half)
    int r64 = t & 63;
    const float* pa = sred + ((hf * 2 + 0) * 64 + r64) * 4;
    const float* pb = sred + ((hf * 2 + 1) * 64 + r64) * 4;
    float s  = pa[0] + pb[0];
    float dd = pa[1] + pb[1];
    float am = fmaxf(fmaxf(pa[2], pb[2]), 1e-20f);
    qscl[t] = 127.f / am;
    int node = bm + t;
    if (node < N_NODES) {
      float2 sc; sc.x = s; sc.y = am * (1.f / 127.f);
      ssc[(size_t)node * 4 + blockIdx.x] = sc;
      s_dst[(size_t)node * 4 + blockIdx.x] = dd;
    }
  }
  __syncthreads();

  // quantize + pack: dword at local offset wn+4r of row lr holds cols
  // {wn + 16*j + r : j=0..3} in bytes 0..3 (permuted layout, see header).
#pragma unroll
  for (int im = 0; im < 4; ++im) {
#pragma unroll
    for (int rr = 0; rr < 4; ++rr) {
      int lr = wm + im * 16 + q * 4 + rr;
      float qs = qscl[lr];
      unsigned int pk = 0;
#pragma unroll
      for (int in = 0; in < 4; ++in) {
        int qv = (int)rintf(acc[im][in][rr] * qs) + 128;
        pk |= (unsigned int)(qv & 255) << (8 * in);
      }
      *(unsigned int*)(h8 + (size_t)(bm + lr) * 512 + bn + wn + 4 * r) = pk;
    }
  }
}

// ---------------------------------------------------------------------------
// Classifier GEMM with fused relu(z)@Wc2 epilogue; single-barrier 2-phase
// prefetch K-loop (same as gemm_fused).
// ---------------------------------------------------------------------------
__global__ __launch_bounds__(256)
void gemm_cls(const unsigned short* __restrict__ A,
              const unsigned short* __restrict__ Bt,
              const float* __restrict__ bc1,
              const float* __restrict__ Wc2,
              float* __restrict__ out,
              int lda)
{
  __shared__ unsigned short As[2][128 * 32];
  __shared__ unsigned short Bs[2][128 * 32];
  const int t    = threadIdx.x;
  const int w    = t >> 6;
  const int lane = t & 63;
  const int r    = lane & 15;
  const int q    = lane >> 4;
  const int bm   = blockIdx.y * 128;
  const int bn   = blockIdx.x * 128;
  const int wm   = (w >> 1) * 64;
  const int wn   = (w & 1) * 64;

  const int ch0 = (w * 2 + 0) * 64 + lane;
  const int ch1 = (w * 2 + 1) * 64 + lane;
  const unsigned short* gA0 = A + (size_t)(bm + (ch0 >> 2)) * lda + (ch0 & 3) * 8;
  const unsigned short* gA1 = A + (size_t)(bm + (ch1 >> 2)) * lda + (ch1 & 3) * 8;
  const unsigned short* gB0 = Bt + (size_t)(bn + (ch0 >> 2)) * lda + (ch0 & 3) * 8;
  const unsigned short* gB1 = Bt + (size_t)(bn + (ch1 >> 2)) * lda + (ch1 & 3) * 8;

  floatx4 acc[4][4] = {};

  int cur = 0;
  stage4(gA0, gA1, gB0, gB1, &As[0][0], &Bs[0][0], w, 0);
  for (int k0 = 0; k0 < lda; k0 += 32) {
    __syncthreads();
    if (k0 + 32 < lda)
      stage4(gA0, gA1, gB0, gB1, &As[cur ^ 1][0], &Bs[cur ^ 1][0], w, k0 + 32);
    short8 af[4], bfr[4];
#pragma unroll
    for (int im = 0; im < 4; ++im)
      af[im] = *(const short8*)(&As[cur][(wm + im * 16 + r) * 32 + q * 8]);
#pragma unroll
    for (int in = 0; in < 4; ++in)
      bfr[in] = *(const short8*)(&Bs[cur][(wn + in * 16 + r) * 32 + q * 8]);
#pragma unroll
    for (int im = 0; im < 4; ++im)
#pragma unroll
      for (int in = 0; in < 4; ++in)
        acc[im][in] = __builtin_amdgcn_mfma_f32_16x16x32_bf16(
            af[im], bfr[in], acc[im][in], 0, 0, 0);
    cur ^= 1;
  }

  float p0[16], p1[16];   // [im*4+rr] -> row bm+wm+im*16+q*4+rr
#pragma unroll
  for (int k = 0; k < 16; ++k) { p0[k] = 0.f; p1[k] = 0.f; }

#pragma unroll
  for (int in = 0; in < 4; ++in) {
    const int col = bn + wn + in * 16 + r;
    const float bv = bc1[col];
    const float w0 = Wc2[col * 2 + 0];
    const float w1 = Wc2[col * 2 + 1];
#pragma unroll
    for (int im = 0; im < 4; ++im)
#pragma unroll
      for (int rr = 0; rr < 4; ++rr) {
        float z = fmaxf(acc[im][in][rr] + bv, 0.f);
        p0[im * 4 + rr] += z * w0;
        p1[im * 4 + rr] += z * w1;
      }
  }
#pragma unroll
  for (int o2 = 1; o2 < 16; o2 <<= 1) {
#pragma unroll
    for (int k = 0; k < 16; ++k) {
      p0[k] += __shfl_xor(p0[k], o2);
      p1[k] += __shfl_xor(p1[k], o2);
    }
  }
  if (r == 0) {
#pragma unroll
    for (int im = 0; im < 4; ++im)
#pragma unroll
      for (int rr = 0; rr < 4; ++rr) {
        int row = bm + wm + im * 16 + q * 4 + rr;
        if (row < N_NODES) {
          atomicAdd(out + (size_t)row * 2,     p0[im * 4 + rr]);
          atomicAdd(out + (size_t)row * 2 + 1, p1[im * 4 + rr]);
        }
      }
  }
}

// ---------------------------------------------------------------------------
// Fused segment-softmax + aggregation + bias + LayerNorm + ELU.
// EXACT round-3 structure (measured 155 us): two-phase chunked edge loop with
// explicit load hoisting -- per 16-edge chunk: (1) ssc score-gather, (2) all
// 16 h8 row loads into a statically-indexed register array (scalar row base
// via readlane + shared lane*8 voffset), (3) next-chunk csr prefetch,
// (4) score chain, (5) accumulate. Rounds 2 (no hoist) and 4 (2-deep
// ping-pong, VGPR 64, occ 40%) both measured SLOWER -- do not restructure.
// h8 decode mapping identical to round 1 (channel = cbase + 16*(k&3)+(k>>2)).
// ---------------------------------------------------------------------------
__global__ __launch_bounds__(256) void k_aggregate(const unsigned char* __restrict__ h8,
                                                   const float2* __restrict__ ssc,
                                                   const int* __restrict__ csr_src,
                                                   const int* __restrict__ off,
                                                   const int* __restrict__ deg,
                                                   const float* __restrict__ s_dst,
                                                   const float* __restrict__ bvec,
                                                   const float* __restrict__ gvec,
                                                   const float* __restrict__ bevec,
                                                   unsigned short* __restrict__ out) {
  int node = blockIdx.x * 4 + (threadIdx.x >> 6);
  int lane = threadIdx.x & 63;
  if (node >= N_NODES) return;
  const int o   = __builtin_amdgcn_readfirstlane(off[node]);
  const int cnt = __builtin_amdgcn_readfirstlane(deg[node]);
  const int head = lane >> 4;
  const int li   = lane & 15;
  const int cbase = head * 128 + ((li & 8) ? 64 : 0) + ((2 * li) & 15);
  const float sdH = s_dst[(size_t)node * 4 + head];

  // acc2[k] = (channel cbase+16k [wx byte k], channel cbase+16k+1 [wy byte k])
  floatx2 acc2[4] = {};
  float sumP = 0.f, sumPS = 0.f;

  int base = 0;
  if (cnt >= 16) {
    int srcl = csr_src[o + li];                    // chunk 0 sources
    for (; base + 16 <= cnt; base += 16) {
      // (1) score gather FIRST (vmcnt-ordered ahead of the row loads)
      float2 fc = ssc[(size_t)srcl * 4 + head];
      // (2) hoist all 16 row loads into registers (static indices)
      uint2 rows[16];
#pragma unroll
      for (int j = 0; j < 16; ++j) {
        int sj = __builtin_amdgcn_readlane(srcl, j);
        rows[j] = *(const uint2*)(h8 + (size_t)sj * 512 + lane * 8);
      }
      // (3) prefetch next chunk's sources
      int srcl_next = srcl;
      if (base + 32 <= cnt) srcl_next = csr_src[o + base + 16 + li];
      // (4) score chain (waits only on fc)
      float e = fc.x + sdH;
      e = (e > 0.f) ? e : NEG_SLOPE * e;
      float p  = __expf(e);
      float ps = p * fc.y;
      sumP += p; sumPS += ps;
      // (5) accumulate
#pragma unroll
      for (int j = 0; j < 16; ++j) {
        float psj = __shfl(ps, j, 16);
        uint2 w = rows[j];
        floatx2 vp = {psj, psj};
        floatx2 b0 = {(float)( w.x        & 255u), (float)( w.y        & 255u)};
        floatx2 b1 = {(float)((w.x >>  8) & 255u), (float)((w.y >>  8) & 255u)};
        floatx2 b2 = {(float)((w.x >> 16) & 255u), (float)((w.y >> 16) & 255u)};
        floatx2 b3 = {(float)( w.x >> 24        ), (float)( w.y >> 24        )};
        acc2[0] += vp * b0;
        acc2[1] += vp * b1;
        acc2[2] += vp * b2;
        acc2[3] += vp * b3;
      }
      srcl = srcl_next;
    }
  }
  // ---- tail chunk (1..15 edges; >=1 guaranteed by self-loop when cnt<16) ----
  int m = cnt - base;
  if (m > 0) {
    int   idx  = (li < m) ? li : (m - 1);          // clamp: stay in-range
    int   srcl = csr_src[o + base + idx];
    float2 fc  = ssc[(size_t)srcl * 4 + head];
    uint2 rows[16];
#pragma unroll
    for (int j = 0; j < 16; ++j) {
      if (j < m) {                                  // wave-uniform predicate
        int sj = __builtin_amdgcn_readlane(srcl, j);
        rows[j] = *(const uint2*)(h8 + (size_t)sj * 512 + lane * 8);
      }
    }
    float e = fc.x + sdH;
    e = (e > 0.f) ? e : NEG_SLOPE * e;
    float p  = (li < m) ? __expf(e) : 0.f;
    float ps = p * fc.y;
    sumP += p; sumPS += ps;
#pragma unroll
    for (int j = 0; j < 16; ++j) {
      if (j < m) {
        float psj = __shfl(ps, j, 16);
        uint2 w = rows[j];
        floatx2 vp = {psj, psj};
        floatx2 b0 = {(float)( w.x        & 255u), (float)( w.y        & 255u)};
        floatx2 b1 = {(float)((w.x >>  8) & 255u), (float)((w.y >>  8) & 255u)};
        floatx2 b2 = {(float)((w.x >> 16) & 255u), (float)((w.y >> 16) & 255u)};
        floatx2 b3 = {(float)( w.x >> 24        ), (float)( w.y >> 24        )};
        acc2[0] += vp * b0;
        acc2[1] += vp * b1;
        acc2[2] += vp * b2;
        acc2[3] += vp * b3;
      }
    }
  }

  // reduce per-lane score partials across the 16-lane head group
#pragma unroll
  for (int o2 = 1; o2 < 16; o2 <<= 1) {
    sumP  += __shfl_xor(sumP,  o2);
    sumPS += __shfl_xor(sumPS, o2);
  }

  float acc[8];
#pragma unroll
  for (int k = 0; k < 4; ++k) { acc[k] = acc2[k].x; acc[k + 4] = acc2[k].y; }

  const float inv = 1.f / sumP;
  float bl[8];
#pragma unroll
  for (int k = 0; k < 4; ++k) {
    float2 v2 = *(const float2*)(bvec + cbase + 16 * k);
    bl[k] = v2.x; bl[k + 4] = v2.y;
  }
#pragma unroll
  for (int k = 0; k < 8; ++k)
    acc[k] = (acc[k] - 128.f * sumPS) * inv + bl[k];

  float ps2 = 0.f, pq = 0.f;
#pragma unroll
  for (int k = 0; k < 8; ++k) { ps2 += acc[k]; pq += acc[k]*acc[k]; }
#pragma unroll
  for (int o2 = 1; o2 < 64; o2 <<= 1) {
    ps2 += __shfl_xor(ps2, o2);
    pq  += __shfl_xor(pq, o2);
  }
  float mu  = ps2 * (1.f/512.f);
  float var = pq * (1.f/512.f) - mu*mu;
  float rstd = rsqrtf(var + LN_EPS);

  float gs[8], es[8];
#pragma unroll
  for (int k = 0; k < 4; ++k) {
    float2 g2 = *(const float2*)(gvec  + cbase + 16 * k);
    float2 e2 = *(const float2*)(bevec + cbase + 16 * k);
    gs[k] = g2.x; gs[k + 4] = g2.y;
    es[k] = e2.x; es[k + 4] = e2.y;
  }

  unsigned short us[8];
#pragma unroll
  for (int k = 0; k < 8; ++k) {
    float y = (acc[k] - mu) * rstd * gs[k] + es[k];
    y = (y > 0.f) ? y : expm1f(y);
    us[k] = f2bf(y);
  }
#pragma unroll
  for (int k = 0; k < 4; ++k) {
    unsigned int wv2 = (unsigned int)us[k] | ((unsigned int)us[k + 4] << 16);
    *(unsigned int*)(out + (size_t)node * D + cbase + 16 * k) = wv2;
  }
}

// ---------------------------------------------------------------------------
extern "C" void kernel_launch(void* const* d_in, const int* in_sizes, int n_in,
                              void* d_out, int out_size, void* d_ws, size_t ws_size,
                              hipStream_t stream) {
  const float* x      = (const float*)d_in[0];
  const int*   ei     = (const int*)  d_in[1];
  const float* W1     = (const float*)d_in[2];
  const float* a_src1 = (const float*)d_in[3];
  const float* a_dst1 = (const float*)d_in[4];
  const float* b1     = (const float*)d_in[5];
  const float* g1     = (const float*)d_in[6];
  const float* be1    = (const float*)d_in[7];
  const float* W2     = (const float*)d_in[8];
  const float* a_src2 = (const float*)d_in[9];
  const float* a_dst2 = (const float*)d_in[10];
  const float* b2     = (const float*)d_in[11];
  const float* g2     = (const float*)d_in[12];
  const float* be2    = (const float*)d_in[13];
  const float* Wc1    = (const float*)d_in[14];
  const float* bc1    = (const float*)d_in[15];
  const float* Wc2    = (const float*)d_in[16];
  const float* bc2    = (const float*)d_in[17];
  float* outp = (float*)d_out;

  char* p = (char*)d_ws;
  auto alloc = [&](size_t bytes) {
    char* r = p;
    p += (bytes + 255) & ~(size_t)255;
    return r;
  };
  unsigned short* obuf = (unsigned short*)alloc((size_t)M_PAD * D * 2); // 102.5 MB
  unsigned short* w1t  = (unsigned short*)alloc((size_t)512 * K1P * 2);
  unsigned short* w2t  = (unsigned short*)alloc((size_t)512 * 512 * 2);
  unsigned short* wc1t = (unsigned short*)alloc((size_t)512 * 512 * 2);
  int*   csr_src = (int*)  alloc((size_t)E_TOT * 4);                    // 6.8 MB
  int*   deg     = (int*)  alloc((size_t)N_NODES * 4);
  int*   off     = (int*)  alloc((size_t)N_NODES * 4);
  int*   pos     = (int*)  alloc((size_t)N_NODES * 4);
  int*   counter = (int*)  alloc(256);
  int*   flag    = (int*)  alloc(256);
  float2* ssc    = (float2*)alloc((size_t)N_NODES * 4 * 8);             // 3.2 MB
  float* s_dst   = (float*)alloc((size_t)N_NODES * 4 * 4);              // 1.6 MB
  unsigned char* h8 = (unsigned char*)alloc((size_t)M_PAD * 512);       // 51.2 MB
  // total ~= 168 MB (hbuf eliminated by the fused GEMM+sdots epilogue)
  // xb aliases obuf (dead after GEMM-1's A-reads, then overwritten by agg-1)
  unsigned short* xb = obuf;

  const int EB = (E_TOT + 255) / 256;
  const int NB = (N_NODES + 255) / 256;
  const int NW = (N_NODES + 3) / 4;
  dim3 gg(4, M_PAD / 128);

  // init (+fused dtype probe) + CSR build + weight conversion
  k_init  <<<NB, 256, 0, stream>>>(ei, deg, counter, flag);
  k_count <<<EB, 256, 0, stream>>>(ei, flag, deg);
  k_alloc <<<NB, 256, 0, stream>>>(deg, off, pos, counter, bc2, outp);
  k_fill  <<<EB, 256, 0, stream>>>(ei, flag, pos, csr_src);

  k_cvt_x <<<(N_NODES * K1P + 255) / 256, 256, 0, stream>>>(x, xb);
  k_cvt_w3<<<dim3(1024, 3), 256, 0, stream>>>(W1, W2, Wc1, w1t, w2t, wc1t);

  // Layer 1 (GEMM writes h8/ssc/s_dst directly; no bf16 h round-trip)
  gemm_fused <<<gg, 256, 0, stream>>>(xb, w1t, a_src1, a_dst1, ssc, s_dst, h8, K1P);
  k_aggregate<<<NW, 256, 0, stream>>>(h8, ssc, csr_src, off, deg,
                                      s_dst, b1, g1, be1, obuf);

  // Layer 2
  gemm_fused <<<gg, 256, 0, stream>>>(obuf, w2t, a_src2, a_dst2, ssc, s_dst, h8, 512);
  k_aggregate<<<NW, 256, 0, stream>>>(h8, ssc, csr_src, off, deg,
                                      s_dst, b2, g2, be2, obuf);

  // Classifier (fused relu + @Wc2 + bc2 via atomics)
  gemm_cls   <<<gg, 256, 0, stream>>>(obuf, wc1t, bc1, Wc2, outp, 512);
}

// Round 7
// 930.221 us; speedup vs baseline: 1.0395x; 1.0395x over previous
//
#include <hip/hip_runtime.h>
#include <math.h>

static constexpr int N_NODES = 100000;
static constexpr int N_EDGES = 1600000;
static constexpr int E_TOT   = N_NODES + N_EDGES;   // edges + self-loops
static constexpr int D   = 512;
static constexpr int FIN = 182;
static constexpr int K1P = 192;                     // FIN padded to mult of 64
static constexpr int M_PAD = 100352;                // 784 * 128 (784 % 8 == 0 for XCD swizzle)
static constexpr float NEG_SLOPE = 0.2f;
static constexpr float LN_EPS = 1e-5f;

typedef __attribute__((ext_vector_type(8))) short short8;
typedef __attribute__((ext_vector_type(4))) float floatx4;
typedef __attribute__((ext_vector_type(2))) float floatx2;

// ---------------- bf16 helpers (storage type: unsigned short) ----------------
__device__ __forceinline__ unsigned short f2bf(float f) {
  unsigned int x = __builtin_bit_cast(unsigned int, f);
  x += 0x7fffu + ((x >> 16) & 1u);   // round-to-nearest-even
  return (unsigned short)(x >> 16);
}
__device__ __forceinline__ void unpack2(unsigned int w, float& lo, float& hi) {
  lo = __builtin_bit_cast(float, w << 16);
  hi = __builtin_bit_cast(float, w & 0xffff0000u);
}

// async global->LDS, 16B per lane; LDS dest = wave-uniform base + lane*16
typedef __attribute__((address_space(1))) const void gv_t;
typedef __attribute__((address_space(3))) void lv_t;
__device__ __forceinline__ void gll16(const void* g, void* l) {
  __builtin_amdgcn_global_load_lds((gv_t*)g, (lv_t*)l, 16, 0, 0);
}

// stage one BK=32 panel pair (A,B) into the given LDS buffers
__device__ __forceinline__ void stage4(const unsigned short* gA0, const unsigned short* gA1,
                                       const unsigned short* gB0, const unsigned short* gB1,
                                       unsigned short* As, unsigned short* Bs, int w, int k0) {
  gll16(gA0 + k0, As + (w * 2 + 0) * 512);
  gll16(gA1 + k0, As + (w * 2 + 1) * 512);
  gll16(gB0 + k0, Bs + (w * 2 + 0) * 512);
  gll16(gB1 + k0, Bs + (w * 2 + 1) * 512);
}

// XCD co-location remap for the GEMM grid (4 heads x 784 row-panels):
// dispatch-linear b -> (head, rblk) such that all 4 head-blocks of one
// row-panel have b = g (mod 8) (same XCD under round-robin assignment) and
// are temporally adjacent -> the shared 128-row A panel is read once from
// L3/HBM and 3x from that XCD's L2. Bijective: b = g + 8*(4*(rblk>>3)+head).
__device__ __forceinline__ void xcd_map(int b, int& head, int& rblk) {
  int g = b & 7;
  int m = b >> 3;          // 0..391
  head = m & 3;
  rblk = g + 8 * (m >> 2); // 0..783
}

// ---------------------------------------------------------------------------
// init (deg zero + counter) with fused edge-index dtype probe (block 0)
// ---------------------------------------------------------------------------
__global__ __launch_bounds__(256) void k_init(const int* __restrict__ ei,
                                              int* __restrict__ deg,
                                              int* __restrict__ counter,
                                              int* __restrict__ flag) {
  int i = blockIdx.x * 256 + threadIdx.x;
  if (i < N_NODES) deg[i] = 0;
  if (blockIdx.x == 0) {
    bool nz = false;
#pragma unroll
    for (int rp = 0; rp < 8; ++rp) {
      int j = threadIdx.x + rp * 256;          // sample edges 0..2047
      nz |= (ei[2 * j + 1] != 0);
    }
    __shared__ int sh[4];
    int wv = threadIdx.x >> 6;
    if ((threadIdx.x & 63) == 0) sh[wv] = 0;
    __syncthreads();
    if (__any(nz) && (threadIdx.x & 63) == 0) sh[wv] = 1;
    __syncthreads();
    if (threadIdx.x == 0) {
      *flag = sh[0] | sh[1] | sh[2] | sh[3];
      *counter = 0;
    }
  }
}

__device__ __forceinline__ int edge_src(const int* ei, int f, int i) {
  return f ? ei[i] : ei[2 * i];
}
__device__ __forceinline__ int edge_dst(const int* ei, int f, int i) {
  return f ? ei[N_EDGES + i] : ei[2 * (N_EDGES + i)];
}

// ---------------------------------------------------------------------------
// CSR build grouped by dst (range order irrelevant -> atomic range alloc)
// ---------------------------------------------------------------------------
__global__ __launch_bounds__(256) void k_count(const int* __restrict__ ei,
                                               const int* __restrict__ flag,
                                               int* __restrict__ deg) {
  int i = blockIdx.x * 256 + threadIdx.x;
  if (i >= E_TOT) return;
  int f = *flag;
  int d = (i < N_EDGES) ? edge_dst(ei, f, i) : (i - N_EDGES);
  atomicAdd(deg + d, 1);
}

// also initializes out[n,0:2] = bc2 (atomic target for gemm_cls epilogue)
__global__ __launch_bounds__(256) void k_alloc(const int* __restrict__ deg,
                                               int* __restrict__ off,
                                               int* __restrict__ pos,
                                               int* __restrict__ counter,
                                               const float* __restrict__ bc2,
                                               float* __restrict__ out) {
  int i = blockIdx.x * 256 + threadIdx.x;
  if (i >= N_NODES) return;
  int r = atomicAdd(counter, deg[i]);
  off[i] = r;
  pos[i] = r;
  float2 v; v.x = bc2[0]; v.y = bc2[1];
  ((float2*)out)[i] = v;
}

__global__ __launch_bounds__(256) void k_fill(const int* __restrict__ ei,
                                              const int* __restrict__ flag,
                                              int* __restrict__ pos,
                                              int* __restrict__ csr_src) {
  int i = blockIdx.x * 256 + threadIdx.x;
  if (i >= E_TOT) return;
  int f = *flag;
  int s, d;
  if (i < N_EDGES) { s = edge_src(ei, f, i); d = edge_dst(ei, f, i); }
  else             { s = d = i - N_EDGES; }
  int slot = atomicAdd(pos + d, 1);
  csr_src[slot] = s;
}

// ---------------------------------------------------------------------------
// conversion kernels (one-shot, tiny)
// ---------------------------------------------------------------------------
// vectorized: one thread converts 8 columns (4x float2 load, 1x 16B store).
// row stride 182*4=728 B is 8-aligned; out stride 192*2=384 B is 16-aligned.
__global__ __launch_bounds__(256) void k_cvt_x(const float* __restrict__ x,
                                               unsigned short* __restrict__ xb) {
  int i = blockIdx.x * 256 + threadIdx.x;
  if (i >= N_NODES * (K1P / 8)) return;
  int row = i / (K1P / 8), c8 = (i - row * (K1P / 8)) * 8;
  const float* xr = x + (size_t)row * FIN + c8;
  float v[8];
#pragma unroll
  for (int j = 0; j < 8; j += 2) {
    if (c8 + j + 1 < FIN) {
      float2 tv = *(const float2*)(xr + j);
      v[j] = tv.x; v[j + 1] = tv.y;
    } else {
      v[j]     = (c8 + j < FIN) ? xr[j] : 0.f;
      v[j + 1] = 0.f;
    }
  }
  unsigned short us[8];
#pragma unroll
  for (int j = 0; j < 8; ++j) us[j] = f2bf(v[j]);
  uint4 w;
  w.x = (unsigned int)us[0] | ((unsigned int)us[1] << 16);
  w.y = (unsigned int)us[2] | ((unsigned int)us[3] << 16);
  w.z = (unsigned int)us[4] | ((unsigned int)us[5] << 16);
  w.w = (unsigned int)us[6] | ((unsigned int)us[7] << 16);
  *(uint4*)(xb + (size_t)row * K1P + c8) = w;
}

// all three weight transposes in one launch (blockIdx.y selects the weight)
__global__ __launch_bounds__(256) void k_cvt_w3(const float* __restrict__ W1,
                                                const float* __restrict__ W2,
                                                const float* __restrict__ Wc1,
                                                unsigned short* __restrict__ w1t,
                                                unsigned short* __restrict__ w2t,
                                                unsigned short* __restrict__ wc1t) {
  int i = blockIdx.x * 256 + threadIdx.x;
  int which = blockIdx.y;
  if (which == 0) {
    if (i >= 512 * K1P) return;
    int n = i / K1P, k = i - n * K1P;
    w1t[i] = f2bf(k < FIN ? W1[(size_t)k * 512 + n] : 0.f);
  } else if (which == 1) {
    if (i >= 512 * 512) return;
    int n = i >> 9, k = i & 511;
    w2t[i] = f2bf(W2[(size_t)k * 512 + n]);
  } else {
    if (i >= 512 * 512) return;
    int n = i >> 9, k = i & 511;
    wc1t[i] = f2bf(Wc1[(size_t)k * 512 + n]);
  }
}

// ---------------------------------------------------------------------------
// Fused GEMM + sdots: h = A @ Bt^T per-block as one full head (128 x 128).
// Round-7 change: XCD co-location remap (see xcd_map) -- 4 head-blocks of a
// row-panel run adjacent on the SAME XCD, turning 3 of 4 A-panel reads into
// local-L2 hits. K-loop: single-barrier 2-phase ping-pong prefetch (round 6,
// neutral but harmless). Epilogue (proven round 1): in-block s_src/s_dst
// dots, per-(node,head) absmax, excess-128 int8 quantization.
// h8 row layout (permuted, per head block of 128 bytes): byte at local
// offset o encodes col (o&64) + 16*(o&3) + ((o>>2)&15).
// ---------------------------------------------------------------------------
__global__ __launch_bounds__(256)
void gemm_fused(const unsigned short* __restrict__ A,
                const unsigned short* __restrict__ Bt,
                const float* __restrict__ a_src,
                const float* __restrict__ a_dst,
                float2* __restrict__ ssc,
                float* __restrict__ s_dst,
                unsigned char* __restrict__ h8,
                int lda)
{
  __shared__ unsigned short As[2][128 * 32];   // ping-pong BK=32 buffers
  __shared__ unsigned short Bs[2][128 * 32];
  const int t    = threadIdx.x;
  const int w    = t >> 6;
  const int lane = t & 63;
  const int r    = lane & 15;
  const int q    = lane >> 4;
  int head, rblk;
  xcd_map(blockIdx.x + 4 * blockIdx.y, head, rblk);
  const int bm   = rblk * 128;
  const int bn   = head * 128;
  const int wm   = (w >> 1) * 64;
  const int wn   = (w & 1) * 64;

  const int ch0 = (w * 2 + 0) * 64 + lane;
  const int ch1 = (w * 2 + 1) * 64 + lane;
  const unsigned short* gA0 = A + (size_t)(bm + (ch0 >> 2)) * lda + (ch0 & 3) * 8;
  const unsigned short* gA1 = A + (size_t)(bm + (ch1 >> 2)) * lda + (ch1 & 3) * 8;
  const unsigned short* gB0 = Bt + (size_t)(bn + (ch0 >> 2)) * lda + (ch0 & 3) * 8;
  const unsigned short* gB1 = Bt + (size_t)(bn + (ch1 >> 2)) * lda + (ch1 & 3) * 8;

  floatx4 acc[4][4] = {};

  int cur = 0;
  stage4(gA0, gA1, gB0, gB1, &As[0][0], &Bs[0][0], w, 0);
  for (int k0 = 0; k0 < lda; k0 += 32) {
    __syncthreads();                       // stage(cur) landed; prev compute done
    if (k0 + 32 < lda)
      stage4(gA0, gA1, gB0, gB1, &As[cur ^ 1][0], &Bs[cur ^ 1][0], w, k0 + 32);
    short8 af[4], bfr[4];
#pragma unroll
    for (int im = 0; im < 4; ++im)
      af[im] = *(const short8*)(&As[cur][(wm + im * 16 + r) * 32 + q * 8]);
#pragma unroll
    for (int in = 0; in < 4; ++in)
      bfr[in] = *(const short8*)(&Bs[cur][(wn + in * 16 + r) * 32 + q * 8]);
#pragma unroll
    for (int im = 0; im < 4; ++im)
#pragma unroll
      for (int in = 0; in < 4; ++in)
        acc[im][in] = __builtin_amdgcn_mfma_f32_16x16x32_bf16(
            af[im], bfr[in], acc[im][in], 0, 0, 0);
    cur ^= 1;
  }
  __syncthreads();                         // all ds_reads done before LDS reuse

  // ---- fused sdots epilogue ----
  // C/D layout: local row lr = wm + im*16 + q*4 + rr, local col c = wn + in*16 + r
  float* sred = (float*)&As[0][0]; // [4 waves][64 rows][4: s_src, s_dst, absmax, pad]
  float* qscl = (float*)&Bs[0][0]; // [128 rows]

  float asv[4], adv[4];
#pragma unroll
  for (int in = 0; in < 4; ++in) {
    asv[in] = a_src[bn + wn + in * 16 + r];
    adv[in] = a_dst[bn + wn + in * 16 + r];
  }
#pragma unroll
  for (int im = 0; im < 4; ++im) {
    float ps_[4], pd_[4], pm_[4];
#pragma unroll
    for (int rr = 0; rr < 4; ++rr) {
      float s = 0.f, d = 0.f, m = 0.f;
#pragma unroll
      for (int in = 0; in < 4; ++in) {
        float v = acc[im][in][rr];
        s += v * asv[in];
        d += v * adv[in];
        m = fmaxf(m, fabsf(v));
      }
      ps_[rr] = s; pd_[rr] = d; pm_[rr] = m;
    }
#pragma unroll
    for (int o2 = 1; o2 < 16; o2 <<= 1) {
#pragma unroll
      for (int rr = 0; rr < 4; ++rr) {
        ps_[rr] += __shfl_xor(ps_[rr], o2);
        pd_[rr] += __shfl_xor(pd_[rr], o2);
        pm_[rr] = fmaxf(pm_[rr], __shfl_xor(pm_[rr], o2));
      }
    }
    if (r == 0) {
#pragma unroll
      for (int rr = 0; rr < 4; ++rr) {
        int r64 = im * 16 + q * 4 + rr;
        sred[(w * 64 + r64) * 4 + 0] = ps_[rr];
        sred[(w * 64 + r64) * 4 + 1] = pd_[rr];
        sred[(w * 64 + r64) * 4 + 2] = pm_[rr];
      }
    }
  }
  __syncthreads();

  if (t < 128) {
    int hf = t >> 6;                 // which wave pair (row half)
    int r64 = t & 63;
    const float* pa = sred + ((hf * 2 + 0) * 64 + r64) * 4;
    const float* pb = sred + ((hf * 2 + 1) * 64 + r64) * 4;
    float s  = pa[0] + pb[0];
    float dd = pa[1] + pb[1];
    float am = fmaxf(fmaxf(pa[2], pb[2]), 1e-20f);
    qscl[t] = 127.f / am;
    int node = bm + t;
    if (node < N_NODES) {
      float2 sc; sc.x = s; sc.y = am * (1.f / 127.f);
      ssc[(size_t)node * 4 + head] = sc;
      s_dst[(size_t)node * 4 + head] = dd;
    }
  }
  __syncthreads();

  // quantize + pack: dword at local offset wn+4r of row lr holds cols
  // {wn + 16*j + r : j=0..3} in bytes 0..3 (permuted layout, see header).
#pragma unroll
  for (int im = 0; im < 4; ++im) {
#pragma unroll
    for (int rr = 0; rr < 4; ++rr) {
      int lr = wm + im * 16 + q * 4 + rr;
      float qs = qscl[lr];
      unsigned int pk = 0;
#pragma unroll
      for (int in = 0; in < 4; ++in) {
        int qv = (int)rintf(acc[im][in][rr] * qs) + 128;
        pk |= (unsigned int)(qv & 255) << (8 * in);
      }
      *(unsigned int*)(h8 + (size_t)(bm + lr) * 512 + bn + wn + 4 * r) = pk;
    }
  }
}

// ---------------------------------------------------------------------------
// Classifier GEMM with fused relu(z)@Wc2 epilogue; XCD co-location remap +
// single-barrier 2-phase prefetch K-loop (same as gemm_fused).
// ---------------------------------------------------------------------------
__global__ __launch_bounds__(256)
void gemm_cls(const unsigned short* __restrict__ A,
              const unsigned short* __restrict__ Bt,
              const float* __restrict__ bc1,
              const float* __restrict__ Wc2,
              float* __restrict__ out,
              int lda)
{
  __shared__ unsigned short As[2][128 * 32];
  __shared__ unsigned short Bs[2][128 * 32];
  const int t    = threadIdx.x;
  const int w    = t >> 6;
  const int lane = t & 63;
  const int r    = lane & 15;
  const int q    = lane >> 4;
  int head, rblk;
  xcd_map(blockIdx.x + 4 * blockIdx.y, head, rblk);
  const int bm   = rblk * 128;
  const int bn   = head * 128;
  const int wm   = (w >> 1) * 64;
  const int wn   = (w & 1) * 64;

  const int ch0 = (w * 2 + 0) * 64 + lane;
  const int ch1 = (w * 2 + 1) * 64 + lane;
  const unsigned short* gA0 = A + (size_t)(bm + (ch0 >> 2)) * lda + (ch0 & 3) * 8;
  const unsigned short* gA1 = A + (size_t)(bm + (ch1 >> 2)) * lda + (ch1 & 3) * 8;
  const unsigned short* gB0 = Bt + (size_t)(bn + (ch0 >> 2)) * lda + (ch0 & 3) * 8;
  const unsigned short* gB1 = Bt + (size_t)(bn + (ch1 >> 2)) * lda + (ch1 & 3) * 8;

  floatx4 acc[4][4] = {};

  int cur = 0;
  stage4(gA0, gA1, gB0, gB1, &As[0][0], &Bs[0][0], w, 0);
  for (int k0 = 0; k0 < lda; k0 += 32) {
    __syncthreads();
    if (k0 + 32 < lda)
      stage4(gA0, gA1, gB0, gB1, &As[cur ^ 1][0], &Bs[cur ^ 1][0], w, k0 + 32);
    short8 af[4], bfr[4];
#pragma unroll
    for (int im = 0; im < 4; ++im)
      af[im] = *(const short8*)(&As[cur][(wm + im * 16 + r) * 32 + q * 8]);
#pragma unroll
    for (int in = 0; in < 4; ++in)
      bfr[in] = *(const short8*)(&Bs[cur][(wn + in * 16 + r) * 32 + q * 8]);
#pragma unroll
    for (int im = 0; im < 4; ++im)
#pragma unroll
      for (int in = 0; in < 4; ++in)
        acc[im][in] = __builtin_amdgcn_mfma_f32_16x16x32_bf16(
            af[im], bfr[in], acc[im][in], 0, 0, 0);
    cur ^= 1;
  }

  float p0[16], p1[16];   // [im*4+rr] -> row bm+wm+im*16+q*4+rr
#pragma unroll
  for (int k = 0; k < 16; ++k) { p0[k] = 0.f; p1[k] = 0.f; }

#pragma unroll
  for (int in = 0; in < 4; ++in) {
    const int col = bn + wn + in * 16 + r;
    const float bv = bc1[col];
    const float w0 = Wc2[col * 2 + 0];
    const float w1 = Wc2[col * 2 + 1];
#pragma unroll
    for (int im = 0; im < 4; ++im)
#pragma unroll
      for (int rr = 0; rr < 4; ++rr) {
        float z = fmaxf(acc[im][in][rr] + bv, 0.f);
        p0[im * 4 + rr] += z * w0;
        p1[im * 4 + rr] += z * w1;
      }
  }
#pragma unroll
  for (int o2 = 1; o2 < 16; o2 <<= 1) {
#pragma unroll
    for (int k = 0; k < 16; ++k) {
      p0[k] += __shfl_xor(p0[k], o2);
      p1[k] += __shfl_xor(p1[k], o2);
    }
  }
  if (r == 0) {
#pragma unroll
    for (int im = 0; im < 4; ++im)
#pragma unroll
      for (int rr = 0; rr < 4; ++rr) {
        int row = bm + wm + im * 16 + q * 4 + rr;
        if (row < N_NODES) {
          atomicAdd(out + (size_t)row * 2,     p0[im * 4 + rr]);
          atomicAdd(out + (size_t)row * 2 + 1, p1[im * 4 + rr]);
        }
      }
  }
}

// ---------------------------------------------------------------------------
// Fused segment-softmax + aggregation + bias + LayerNorm + ELU.
// EXACT round-3 structure (measured 155 us): two-phase chunked edge loop with
// explicit load hoisting -- per 16-edge chunk: (1) ssc score-gather, (2) all
// 16 h8 row loads into a statically-indexed register array (scalar row base
// via readlane + shared lane*8 voffset), (3) next-chunk csr prefetch,
// (4) score chain, (5) accumulate. Rounds 2 (no hoist) and 4 (2-deep
// ping-pong, VGPR 64, occ 40%) both measured SLOWER -- do not restructure.
// h8 decode mapping identical to round 1 (channel = cbase + 16*(k&3)+(k>>2)).
// ---------------------------------------------------------------------------
__global__ __launch_bounds__(256) void k_aggregate(const unsigned char* __restrict__ h8,
                                                   const float2* __restrict__ ssc,
                                                   const int* __restrict__ csr_src,
                                                   const int* __restrict__ off,
                                                   const int* __restrict__ deg,
                                                   const float* __restrict__ s_dst,
                                                   const float* __restrict__ bvec,
                                                   const float* __restrict__ gvec,
                                                   const float* __restrict__ bevec,
                                                   unsigned short* __restrict__ out) {
  int node = blockIdx.x * 4 + (threadIdx.x >> 6);
  int lane = threadIdx.x & 63;
  if (node >= N_NODES) return;
  const int o   = __builtin_amdgcn_readfirstlane(off[node]);
  const int cnt = __builtin_amdgcn_readfirstlane(deg[node]);
  const int head = lane >> 4;
  const int li   = lane & 15;
  const int cbase = head * 128 + ((li & 8) ? 64 : 0) + ((2 * li) & 15);
  const float sdH = s_dst[(size_t)node * 4 + head];

  // acc2[k] = (channel cbase+16k [wx byte k], channel cbase+16k+1 [wy byte k])
  floatx2 acc2[4] = {};
  float sumP = 0.f, sumPS = 0.f;

  int base = 0;
  if (cnt >= 16) {
    int srcl = csr_src[o + li];                    // chunk 0 sources
    for (; base + 16 <= cnt; base += 16) {
      // (1) score gather FIRST (vmcnt-ordered ahead of the row loads)
      float2 fc = ssc[(size_t)srcl * 4 + head];
      // (2) hoist all 16 row loads into registers (static indices)
      uint2 rows[16];
#pragma unroll
      for (int j = 0; j < 16; ++j) {
        int sj = __builtin_amdgcn_readlane(srcl, j);
        rows[j] = *(const uint2*)(h8 + (size_t)sj * 512 + lane * 8);
      }
      // (3) prefetch next chunk's sources
      int srcl_next = srcl;
      if (base + 32 <= cnt) srcl_next = csr_src[o + base + 16 + li];
      // (4) score chain (waits only on fc)
      float e = fc.x + sdH;
      e = (e > 0.f) ? e : NEG_SLOPE * e;
      float p  = __expf(e);
      float ps = p * fc.y;
      sumP += p; sumPS += ps;
      // (5) accumulate
#pragma unroll
      for (int j = 0; j < 16; ++j) {
        float psj = __shfl(ps, j, 16);
        uint2 w = rows[j];
        floatx2 vp = {psj, psj};
        floatx2 b0 = {(float)( w.x        & 255u), (float)( w.y        & 255u)};
        floatx2 b1 = {(float)((w.x >>  8) & 255u), (float)((w.y >>  8) & 255u)};
        floatx2 b2 = {(float)((w.x >> 16) & 255u), (float)((w.y >> 16) & 255u)};
        floatx2 b3 = {(float)( w.x >> 24        ), (float)( w.y >> 24        )};
        acc2[0] += vp * b0;
        acc2[1] += vp * b1;
        acc2[2] += vp * b2;
        acc2[3] += vp * b3;
      }
      srcl = srcl_next;
    }
  }
  // ---- tail chunk (1..15 edges; >=1 guaranteed by self-loop when cnt<16) ----
  int m = cnt - base;
  if (m > 0) {
    int   idx  = (li < m) ? li : (m - 1);          // clamp: stay in-range
    int   srcl = csr_src[o + base + idx];
    float2 fc  = ssc[(size_t)srcl * 4 + head];
    uint2 rows[16];
#pragma unroll
    for (int j = 0; j < 16; ++j) {
      if (j < m) {                                  // wave-uniform predicate
        int sj = __builtin_amdgcn_readlane(srcl, j);
        rows[j] = *(const uint2*)(h8 + (size_t)sj * 512 + lane * 8);
      }
    }
    float e = fc.x + sdH;
    e = (e > 0.f) ? e : NEG_SLOPE * e;
    float p  = (li < m) ? __expf(e) : 0.f;
    float ps = p * fc.y;
    sumP += p; sumPS += ps;
#pragma unroll
    for (int j = 0; j < 16; ++j) {
      if (j < m) {
        float psj = __shfl(ps, j, 16);
        uint2 w = rows[j];
        floatx2 vp = {psj, psj};
        floatx2 b0 = {(float)( w.x        & 255u), (float)( w.y        & 255u)};
        floatx2 b1 = {(float)((w.x >>  8) & 255u), (float)((w.y >>  8) & 255u)};
        floatx2 b2 = {(float)((w.x >> 16) & 255u), (float)((w.y >> 16) & 255u)};
        floatx2 b3 = {(float)( w.x >> 24        ), (float)( w.y >> 24        )};
        acc2[0] += vp * b0;
        acc2[1] += vp * b1;
        acc2[2] += vp * b2;
        acc2[3] += vp * b3;
      }
    }
  }

  // reduce per-lane score partials across the 16-lane head group
#pragma unroll
  for (int o2 = 1; o2 < 16; o2 <<= 1) {
    sumP  += __shfl_xor(sumP,  o2);
    sumPS += __shfl_xor(sumPS, o2);
  }

  float acc[8];
#pragma unroll
  for (int k = 0; k < 4; ++k) { acc[k] = acc2[k].x; acc[k + 4] = acc2[k].y; }

  const float inv = 1.f / sumP;
  float bl[8];
#pragma unroll
  for (int k = 0; k < 4; ++k) {
    float2 v2 = *(const float2*)(bvec + cbase + 16 * k);
    bl[k] = v2.x; bl[k + 4] = v2.y;
  }
#pragma unroll
  for (int k = 0; k < 8; ++k)
    acc[k] = (acc[k] - 128.f * sumPS) * inv + bl[k];

  float ps2 = 0.f, pq = 0.f;
#pragma unroll
  for (int k = 0; k < 8; ++k) { ps2 += acc[k]; pq += acc[k]*acc[k]; }
#pragma unroll
  for (int o2 = 1; o2 < 64; o2 <<= 1) {
    ps2 += __shfl_xor(ps2, o2);
    pq  += __shfl_xor(pq, o2);
  }
  float mu  = ps2 * (1.f/512.f);
  float var = pq * (1.f/512.f) - mu*mu;
  float rstd = rsqrtf(var + LN_EPS);

  float gs[8], es[8];
#pragma unroll
  for (int k = 0; k < 4; ++k) {
    float2 g2 = *(const float2*)(gvec  + cbase + 16 * k);
    float2 e2 = *(const float2*)(bevec + cbase + 16 * k);
    gs[k] = g2.x; gs[k + 4] = g2.y;
    es[k] = e2.x; es[k + 4] = e2.y;
  }

  unsigned short us[8];
#pragma unroll
  for (int k = 0; k < 8; ++k) {
    float y = (acc[k] - mu) * rstd * gs[k] + es[k];
    y = (y > 0.f) ? y : expm1f(y);
    us[k] = f2bf(y);
  }
#pragma unroll
  for (int k = 0; k < 4; ++k) {
    unsigned int wv2 = (unsigned int)us[k] | ((unsigned int)us[k + 4] << 16);
    *(unsigned int*)(out + (size_t)node * D + cbase + 16 * k) = wv2;
  }
}

// ---------------------------------------------------------------------------
extern "C" void kernel_launch(void* const* d_in, const int* in_sizes, int n_in,
                              void* d_out, int out_size, void* d_ws, size_t ws_size,
                              hipStream_t stream) {
  const float* x      = (const float*)d_in[0];
  const int*   ei     = (const int*)  d_in[1];
  const float* W1     = (const float*)d_in[2];
  const float* a_src1 = (const float*)d_in[3];
  const float* a_dst1 = (const float*)d_in[4];
  const float* b1     = (const float*)d_in[5];
  const float* g1     = (const float*)d_in[6];
  const float* be1    = (const float*)d_in[7];
  const float* W2     = (const float*)d_in[8];
  const float* a_src2 = (const float*)d_in[9];
  const float* a_dst2 = (const float*)d_in[10];
  const float* b2     = (const float*)d_in[11];
  const float* g2     = (const float*)d_in[12];
  const float* be2    = (const float*)d_in[13];
  const float* Wc1    = (const float*)d_in[14];
  const float* bc1    = (const float*)d_in[15];
  const float* Wc2    = (const float*)d_in[16];
  const float* bc2    = (const float*)d_in[17];
  float* outp = (float*)d_out;

  char* p = (char*)d_ws;
  auto alloc = [&](size_t bytes) {
    char* r = p;
    p += (bytes + 255) & ~(size_t)255;
    return r;
  };
  unsigned short* obuf = (unsigned short*)alloc((size_t)M_PAD * D * 2); // 102.8 MB
  unsigned short* w1t  = (unsigned short*)alloc((size_t)512 * K1P * 2);
  unsigned short* w2t  = (unsigned short*)alloc((size_t)512 * 512 * 2);
  unsigned short* wc1t = (unsigned short*)alloc((size_t)512 * 512 * 2);
  int*   csr_src = (int*)  alloc((size_t)E_TOT * 4);                    // 6.8 MB
  int*   deg     = (int*)  alloc((size_t)N_NODES * 4);
  int*   off     = (int*)  alloc((size_t)N_NODES * 4);
  int*   pos     = (int*)  alloc((size_t)N_NODES * 4);
  int*   counter = (int*)  alloc(256);
  int*   flag    = (int*)  alloc(256);
  float2* ssc    = (float2*)alloc((size_t)N_NODES * 4 * 8);             // 3.2 MB
  float* s_dst   = (float*)alloc((size_t)N_NODES * 4 * 4);              // 1.6 MB
  unsigned char* h8 = (unsigned char*)alloc((size_t)M_PAD * 512);       // 51.4 MB
  // total ~= 168 MB (hbuf eliminated by the fused GEMM+sdots epilogue)
  // xb aliases obuf (dead after GEMM-1's A-reads, then overwritten by agg-1)
  unsigned short* xb = obuf;

  const int EB = (E_TOT + 255) / 256;
  const int NB = (N_NODES + 255) / 256;
  const int NW = (N_NODES + 3) / 4;
  dim3 gg(4, M_PAD / 128);

  // init (+fused dtype probe) + CSR build + weight conversion
  k_init  <<<NB, 256, 0, stream>>>(ei, deg, counter, flag);
  k_count <<<EB, 256, 0, stream>>>(ei, flag, deg);
  k_alloc <<<NB, 256, 0, stream>>>(deg, off, pos, counter, bc2, outp);
  k_fill  <<<EB, 256, 0, stream>>>(ei, flag, pos, csr_src);

  k_cvt_x <<<(N_NODES * (K1P / 8) + 255) / 256, 256, 0, stream>>>(x, xb);
  k_cvt_w3<<<dim3(1024, 3), 256, 0, stream>>>(W1, W2, Wc1, w1t, w2t, wc1t);

  // Layer 1 (GEMM writes h8/ssc/s_dst directly; no bf16 h round-trip)
  gemm_fused <<<gg, 256, 0, stream>>>(xb, w1t, a_src1, a_dst1, ssc, s_dst, h8, K1P);
  k_aggregate<<<NW, 256, 0, stream>>>(h8, ssc, csr_src, off, deg,
                                      s_dst, b1, g1, be1, obuf);

  // Layer 2
  gemm_fused <<<gg, 256, 0, stream>>>(obuf, w2t, a_src2, a_dst2, ssc, s_dst, h8, 512);
  k_aggregate<<<NW, 256, 0, stream>>>(h8, ssc, csr_src, off, deg,
                                      s_dst, b2, g2, be2, obuf);

  // Classifier (fused relu + @Wc2 + bc2 via atomics)
  gemm_cls   <<<gg, 256, 0, stream>>>(obuf, wc1t, bc1, Wc2, outp, 512);
}